// Round 11
// baseline (555.867 us; speedup 1.0000x reference)
//
#include <hip/hip_runtime.h>
#include <hip/hip_fp16.h>

#define NN 50000
#define NE 1600000
#define NR 8
#define D 128
#define DOUT 64
#define NCB ((NN + 63) / 64)          // 782 coarse buckets (dst>>6)
#define NBLK 256                      // partition blocks
#define CH ((NE + NBLK - 1) / NBLK)   // 6250 edges per partition block
#define GRIDM ((NN + 63) / 64)        // 782 M-tiles for MFMA GEMM

typedef __attribute__((ext_vector_type(8))) _Float16 f16x8;
typedef __attribute__((ext_vector_type(4))) float f32x4;

__device__ __forceinline__ unsigned short f2h(float x) {
    return __half_as_ushort(__float2half(x));   // v_cvt_f16_f32, RNE
}
__device__ __forceinline__ unsigned pack2h(float a, float b) {
    return (unsigned)f2h(a) | ((unsigned)f2h(b) << 16);
}
__device__ __forceinline__ __half2 u2h(unsigned u) {
    union { unsigned u; __half2 h; } c; c.u = u; return c.h;
}
__device__ __forceinline__ unsigned h2u(__half2 h) {
    union { __half2 h; unsigned u; } c; c.h = h; return c.u;
}

// async global->LDS, 16B per lane; LDS dest = wave-uniform base + lane*16
__device__ __forceinline__ void gl2lds16(const void* g, void* l) {
    __builtin_amdgcn_global_load_lds(
        (const __attribute__((address_space(1))) unsigned int*)g,
        (__attribute__((address_space(3))) unsigned int*)l, 16, 0, 0);
}

// ---------------- CSR build: atomic-free radix partition ----------------
__global__ __launch_bounds__(1024)
void k_cnt(const int* __restrict__ ei, int* __restrict__ cntmat) {
    __shared__ int h[NCB];
    const int blk = blockIdx.x, tid = threadIdx.x;
    for (int i = tid; i < NCB; i += 1024) h[i] = 0;
    __syncthreads();
    const int e0 = blk * CH, e1 = min(e0 + CH, NE);
    for (int e = e0 + tid; e < e1; e += 1024)
        atomicAdd(&h[ei[NE + e] >> 6], 1);
    __syncthreads();
    for (int i = tid; i < NCB; i += 1024) cntmat[i * NBLK + blk] = h[i];
}

__global__ __launch_bounds__(64)
void k_colscan(int* __restrict__ cntmat, int* __restrict__ colsum) {
    const int b = blockIdx.x, lane = threadIdx.x;
    int4 v = *reinterpret_cast<int4*>(cntmat + b * NBLK + lane * 4);
    int s = v.x + v.y + v.z + v.w;
    int e = s;
    #pragma unroll
    for (int o = 1; o < 64; o <<= 1) {
        int y = __shfl_up(e, o);
        if (lane >= o) e += y;
    }
    int excl = e - s;
    int4 w;
    w.x = excl; w.y = excl + v.x; w.z = excl + v.x + v.y; w.w = excl + v.x + v.y + v.z;
    *reinterpret_cast<int4*>(cntmat + b * NBLK + lane * 4) = w;
    if (lane == 63) colsum[b] = e;
}

__global__ __launch_bounds__(1024)
void k_bscan(const int* __restrict__ colsum, int* __restrict__ bstart) {
    __shared__ int s[1024];
    int t = threadIdx.x;
    int v = (t < NCB) ? colsum[t] : 0;
    s[t] = v;
    __syncthreads();
    for (int o = 1; o < 1024; o <<= 1) {
        int x = (t >= o) ? s[t - o] : 0;
        __syncthreads();
        s[t] += x;
        __syncthreads();
    }
    if (t < NCB) bstart[t] = s[t] - v;
    if (t == 0) bstart[NCB] = NE;
}

// pack: dstlo(6) << 19 | rel(3) << 16 | src(16)
__global__ __launch_bounds__(1024)
void k_pscatter(const int* __restrict__ ei, const int* __restrict__ et,
                const int* __restrict__ cntmat, const int* __restrict__ bstart,
                int* __restrict__ bck) {
    __shared__ int cur[NCB];
    const int blk = blockIdx.x, tid = threadIdx.x;
    for (int i = tid; i < NCB; i += 1024)
        cur[i] = bstart[i] + cntmat[i * NBLK + blk];
    __syncthreads();
    const int e0 = blk * CH, e1 = min(e0 + CH, NE);
    for (int e = e0 + tid; e < e1; e += 1024) {
        int dst = ei[NE + e];
        int pk = ((dst & 63) << 19) | (et[e] << 16) | ei[e];
        int p = atomicAdd(&cur[dst >> 6], 1);
        bck[p] = pk;
    }
}

// per coarse bucket: 512-bin (dstlo*8+rel) LDS hist/scan -> off8 CSR, rel-sorted scatter
__global__ __launch_bounds__(256)
void k_build(const int* __restrict__ bck, const int* __restrict__ cbase,
             int* __restrict__ off8, float* __restrict__ invdeg,
             int* __restrict__ esrcF) {
    __shared__ int cnt[512];
    __shared__ int cur[512];
    __shared__ int wtot[4];
    __shared__ int sb[2];
    const int b = blockIdx.x;
    const int tid = threadIdx.x;
    const int wid = tid >> 6, lane = tid & 63;
    cnt[tid] = 0; cnt[tid + 256] = 0;
    if (tid == 0) { sb[0] = cbase[b]; sb[1] = cbase[b + 1]; }
    __syncthreads();
    const int s0 = sb[0], s1 = sb[1];
    for (int i = s0 + tid; i < s1; i += 256)
        atomicAdd(&cnt[(bck[i] >> 16) & 511], 1);
    __syncthreads();
    int c0 = cnt[2 * tid], c1 = cnt[2 * tid + 1];
    int ps = c0 + c1;
    int x = ps;
    #pragma unroll
    for (int o = 1; o < 64; o <<= 1) {
        int y = __shfl_up(x, o);
        if (lane >= o) x += y;
    }
    if (lane == 63) wtot[wid] = x;
    __syncthreads();
    int woff = 0;
    #pragma unroll
    for (int w2 = 0; w2 < 4; ++w2) woff += (w2 < wid) ? wtot[w2] : 0;
    int base = s0 + woff + x - ps;
    cur[2 * tid] = base;
    cur[2 * tid + 1] = base + c0;
    off8[(size_t)b * 512 + 2 * tid] = base;
    off8[(size_t)b * 512 + 2 * tid + 1] = base + c0;
    if (tid < 64) {
        int gd = b * 64 + tid;
        if (gd < NN) {
            int dsum = 0;
            #pragma unroll
            for (int r = 0; r < 8; ++r) dsum += cnt[tid * 8 + r];
            invdeg[gd] = 1.0f / (float)max(dsum, 1);
        }
    }
    __syncthreads();
    for (int i = s0 + tid; i < s1; i += 256) {
        int pk = bck[i];
        int p = atomicAdd(&cur[(pk >> 16) & 511], 1);
        esrcF[p] = pk & 0xFFFF;   // src only (rel implied by position)
    }
}

// ---------------- prep: fp32 -> f16 tables (weights: chunk-blocked + XOR-swizzled) ----

__global__ void k_prep_x(const float* __restrict__ X, unsigned* __restrict__ Xt) {
    int i = blockIdx.x * blockDim.x + threadIdx.x;
    if (i < NN * 64) {
        float2 f = reinterpret_cast<const float2*>(X)[i];
        Xt[i] = pack2h(f.x, f.y);
    }
}

// dst layout: [kc][n][e] where e = (k&127) ^ ((n&7)<<3)
__global__ void k_prep_wcat(const float* __restrict__ W0, const float* __restrict__ Wr,
                            unsigned short* __restrict__ dst) {
    int i = blockIdx.x * blockDim.x + threadIdx.x;
    if (i < 128 * 1152) {
        int n = i / 1152, k = i % 1152;
        float v = (k < 128) ? W0[k * 128 + n] : Wr[(k - 128) * 128 + n];
        int kc = k >> 7, kl = k & 127;
        int e = kl ^ ((n & 7) << 3);
        dst[((size_t)kc * 128 + n) * 128 + e] = f2h(v);
    }
}

// src [128][N] f32 -> dst [N][128] f16, swizzled: dst[n][k ^ ((n&7)<<3)]
__global__ void k_prep_wt(const float* __restrict__ src, unsigned short* __restrict__ dst,
                          int N) {
    int i = blockIdx.x * blockDim.x + threadIdx.x;
    if (i < N * 128) {
        int n = i >> 7, k = i & 127;
        int e = k ^ ((n & 7) << 3);
        dst[n * 128 + e] = f2h(src[k * N + n]);
    }
}

// ---------------- aggregation: one wave per dst ----------------

// wide per-relation agg, rel-sorted subsegments, packed-f16 accumulate
__global__ __launch_bounds__(256)
void k_aggw(const unsigned* __restrict__ Xt, unsigned* __restrict__ AW,
            const int* __restrict__ off8, const int* __restrict__ esrcF) {
    const int wid = threadIdx.x >> 6, lane = threadIdx.x & 63;
    const int v = blockIdx.x * 4 + wid;
    if (v >= NN) return;
    unsigned* o = AW + (size_t)v * 512 + lane;
    int s = off8[v * 8];
    for (int r = 0; r < 8; ++r) {
        const int e = off8[v * 8 + r + 1];
        __half2 acc = u2h(0u);
        for (int j = s; j < e; j += 4) {
            int p0 = __builtin_amdgcn_readfirstlane(esrcF[j]);
            int p1 = __builtin_amdgcn_readfirstlane(esrcF[j + 1]);
            int p2 = __builtin_amdgcn_readfirstlane(esrcF[j + 2]);
            int p3 = __builtin_amdgcn_readfirstlane(esrcF[j + 3]);
            unsigned u0 = Xt[(unsigned)(p0 & 0xffff) * 64 + lane];
            unsigned u1 = Xt[(unsigned)(p1 & 0xffff) * 64 + lane];
            unsigned u2 = Xt[(unsigned)(p2 & 0xffff) * 64 + lane];
            unsigned u3 = Xt[(unsigned)(p3 & 0xffff) * 64 + lane];
            acc = __hadd2(acc, u2h(u0));
            if (j + 1 < e) acc = __hadd2(acc, u2h(u1));
            if (j + 2 < e) acc = __hadd2(acc, u2h(u2));
            if (j + 3 < e) acc = __hadd2(acc, u2h(u3));
        }
        o[r * 64] = h2u(acc);
        s = e;
    }
}

// full-graph agg with invdeg scale; f32 accumulators (long segments)
__global__ __launch_bounds__(256)
void k_aggh(const unsigned* __restrict__ Xt, unsigned* __restrict__ AH,
            const int* __restrict__ off8, const int* __restrict__ esrcF,
            const float* __restrict__ invdeg) {
    const int wid = threadIdx.x >> 6, lane = threadIdx.x & 63;
    const int v = blockIdx.x * 4 + wid;
    if (v >= NN) return;
    const int s = off8[v * 8], e = off8[v * 8 + 8];
    float a0 = 0.f, a1 = 0.f;
    for (int j = s; j < e; j += 8) {
        int p0 = __builtin_amdgcn_readfirstlane(esrcF[j]);
        int p1 = __builtin_amdgcn_readfirstlane(esrcF[j + 1]);
        int p2 = __builtin_amdgcn_readfirstlane(esrcF[j + 2]);
        int p3 = __builtin_amdgcn_readfirstlane(esrcF[j + 3]);
        int p4 = __builtin_amdgcn_readfirstlane(esrcF[j + 4]);
        int p5 = __builtin_amdgcn_readfirstlane(esrcF[j + 5]);
        int p6 = __builtin_amdgcn_readfirstlane(esrcF[j + 6]);
        int p7 = __builtin_amdgcn_readfirstlane(esrcF[j + 7]);
        unsigned u0 = Xt[(unsigned)(p0 & 0xffff) * 64 + lane];
        unsigned u1 = Xt[(unsigned)(p1 & 0xffff) * 64 + lane];
        unsigned u2 = Xt[(unsigned)(p2 & 0xffff) * 64 + lane];
        unsigned u3 = Xt[(unsigned)(p3 & 0xffff) * 64 + lane];
        unsigned u4 = Xt[(unsigned)(p4 & 0xffff) * 64 + lane];
        unsigned u5 = Xt[(unsigned)(p5 & 0xffff) * 64 + lane];
        unsigned u6 = Xt[(unsigned)(p6 & 0xffff) * 64 + lane];
        unsigned u7 = Xt[(unsigned)(p7 & 0xffff) * 64 + lane];
        __half2 h0 = u2h(u0);
        a0 += __low2float(h0); a1 += __high2float(h0);
        if (j + 1 < e) { __half2 h = u2h(u1); a0 += __low2float(h); a1 += __high2float(h); }
        if (j + 2 < e) { __half2 h = u2h(u2); a0 += __low2float(h); a1 += __high2float(h); }
        if (j + 3 < e) { __half2 h = u2h(u3); a0 += __low2float(h); a1 += __high2float(h); }
        if (j + 4 < e) { __half2 h = u2h(u4); a0 += __low2float(h); a1 += __high2float(h); }
        if (j + 5 < e) { __half2 h = u2h(u5); a0 += __low2float(h); a1 += __high2float(h); }
        if (j + 6 < e) { __half2 h = u2h(u6); a0 += __low2float(h); a1 += __high2float(h); }
        if (j + 7 < e) { __half2 h = u2h(u7); a0 += __low2float(h); a1 += __high2float(h); }
    }
    float inv = invdeg[v];
    AH[(size_t)v * 64 + lane] = pack2h(a0 * inv, a1 * inv);
}

// ---------------- f16 MFMA GEMM: LDS-staged B (swizzled), chunked K ----------------
template <int N, int MODE, int NCHUNK>
__global__ __launch_bounds__(256)
void k_mfma(const short* __restrict__ A0, const short* __restrict__ A1,
            const short* __restrict__ Wc,
            float* __restrict__ Yf, unsigned short* __restrict__ Ybf,
            const float* __restrict__ aux, const float* __restrict__ bias,
            const float* __restrict__ alpha_p, const float* __restrict__ invdeg) {
    constexpr int NT = N / 16;
    constexpr int NIT = N / 16;          // staging iters
    __shared__ short Bs[N * 128];
    const int tid = threadIdx.x;
    const int wave = tid >> 6;
    const int lane = tid & 63;
    const int lr = lane & 15;
    const int lk = (lane >> 4) * 8;
    const int rowBase = blockIdx.x * 64 + wave * 16;
    const int r0 = min(rowBase + lr, NN - 1);

    f32x4 acc[NT];
    #pragma unroll
    for (int nt = 0; nt < NT; ++nt) acc[nt] = f32x4{0.f, 0.f, 0.f, 0.f};

    for (int kc = 0; kc < NCHUNK; ++kc) {
        {
            const char* gs = (const char*)Wc + (size_t)kc * N * 256
                             + (wave * NIT) * 1024 + lane * 16;
            char* ls = (char*)Bs + (wave * NIT) * 1024;
            #pragma unroll
            for (int j = 0; j < NIT; ++j)
                gl2lds16(gs + j * 1024, ls + j * 1024);
        }
        const short* abase = (kc == 0) ? (A0 + (size_t)r0 * 128)
                                       : (A1 + (size_t)r0 * 1024 + (kc - 1) * 128);
        f16x8 a0 = *reinterpret_cast<const f16x8*>(abase + 0 + lk);
        f16x8 a1 = *reinterpret_cast<const f16x8*>(abase + 32 + lk);
        f16x8 a2 = *reinterpret_cast<const f16x8*>(abase + 64 + lk);
        f16x8 a3 = *reinterpret_cast<const f16x8*>(abase + 96 + lk);
        __syncthreads();

        #pragma unroll
        for (int s = 0; s < 4; ++s) {
            f16x8 a = (s == 0) ? a0 : (s == 1) ? a1 : (s == 2) ? a2 : a3;
            #pragma unroll
            for (int nt = 0; nt < NT; ++nt) {
                const int c = nt * 16 + lr;
                const int e0 = (s * 32 + lk) ^ ((c & 7) << 3);
                f16x8 b = *reinterpret_cast<const f16x8*>(
                    (const char*)Bs + c * 256 + e0 * 2);
                acc[nt] = __builtin_amdgcn_mfma_f32_16x16x32_f16(a, b, acc[nt], 0, 0, 0);
            }
        }
        __syncthreads();
    }

    const float al = (MODE == 1) ? *alpha_p : 0.f;
    #pragma unroll
    for (int j = 0; j < 4; ++j) {
        const int row = rowBase + (lane >> 4) * 4 + j;
        if (row >= NN) continue;
        float idg = (MODE == 0) ? invdeg[row] : 0.f;
        #pragma unroll
        for (int nt = 0; nt < NT; ++nt) {
            const int col = nt * 16 + lr;
            float v = acc[nt][j];
            if (MODE == 0) {
                v = fmaxf(v * idg, 0.f);
                Yf[(size_t)row * 128 + col] = v;
                Ybf[(size_t)row * 128 + col] = f2h(v);
            } else if (MODE == 1) {
                v = aux[(size_t)row * 128 + col] + al * (v + bias[col]);
                Ybf[(size_t)row * 128 + col] = f2h(v);
            } else {
                Yf[(size_t)row * 64 + col] = v + bias[col];
            }
        }
    }
}

// ---------------- launch ----------------

extern "C" void kernel_launch(void* const* d_in, const int* in_sizes, int n_in,
                              void* d_out, int out_size, void* d_ws, size_t ws_size,
                              hipStream_t stream) {
    const float* X   = (const float*)d_in[0];
    const int*   ei  = (const int*)d_in[1];
    const int*   et  = (const int*)d_in[2];
    const float* W1  = (const float*)d_in[3];
    const float* W01 = (const float*)d_in[4];
    const float* al1 = (const float*)d_in[5];
    const float* p1w = (const float*)d_in[6];
    const float* p1b = (const float*)d_in[7];
    const float* W2  = (const float*)d_in[8];
    const float* W02 = (const float*)d_in[9];
    const float* al2 = (const float*)d_in[10];
    const float* p2w = (const float*)d_in[11];
    const float* p2b = (const float*)d_in[12];
    const float* ow  = (const float*)d_in[13];
    const float* ob  = (const float*)d_in[14];
    float* out = (float*)d_out;

    char* wsp = (char*)d_ws;
    size_t o = 0;
    auto take = [&](size_t bytes) -> void* {
        void* p = wsp + o;
        o = (o + bytes + 255) & ~(size_t)255;
        return p;
    };
    int*      cntmat = (int*)take((size_t)NCB * NBLK * 4);
    int*      colsum = (int*)take((size_t)NCB * 4);
    int*      bstart = (int*)take((size_t)(NCB + 1) * 4);
    int*      off8   = (int*)take((size_t)(NCB * 512 + 1) * 4);  // fine CSR (dst,rel)
    float*    invdeg = (float*)take((size_t)NN * 4);
    int*      bck    = (int*)take((size_t)NE * 4);
    int*      esrcF  = (int*)take((size_t)(NE + 8) * 4);     // +8 overread slack
    unsigned* T1     = (unsigned*)take((size_t)NN * 64 * 4); // Xf16  -> H2f16
    unsigned* T2     = (unsigned*)take((size_t)NN * 64 * 4); // Hf16  -> G2f16
    unsigned* T3     = (unsigned*)take((size_t)NN * 64 * 4); // G1f16
    unsigned* AW     = (unsigned*)take((size_t)NN * 512 * 4);
    unsigned* AH     = (unsigned*)take((size_t)NN * 64 * 4);
    float*    Hf     = (float*)take((size_t)NN * 128 * 4);
    unsigned short* WtC1 = (unsigned short*)take((size_t)128 * 1152 * 2);
    unsigned short* WtC2 = (unsigned short*)take((size_t)128 * 1152 * 2);
    unsigned short* Wtp1 = (unsigned short*)take((size_t)128 * 128 * 2);
    unsigned short* Wtp2 = (unsigned short*)take((size_t)128 * 128 * 2);
    unsigned short* WtO  = (unsigned short*)take((size_t)64 * 128 * 2);
    if (o > ws_size) return;

    // ---- CSR build (atomic-free radix partition; rel-sorted fine CSR) ----
    k_cnt<<<NBLK, 1024, 0, stream>>>(ei, cntmat);
    k_colscan<<<NCB, 64, 0, stream>>>(cntmat, colsum);
    k_bscan<<<1, 1024, 0, stream>>>(colsum, bstart);
    k_pscatter<<<NBLK, 1024, 0, stream>>>(ei, et, cntmat, bstart, bck);
    k_build<<<NCB, 256, 0, stream>>>(bck, bstart, off8, invdeg, esrcF);

    // ---- prep ----
    k_prep_x<<<(NN * 64 + 255) / 256, 256, 0, stream>>>(X, T1);
    k_prep_wcat<<<(128 * 1152 + 255) / 256, 256, 0, stream>>>(W01, W1, WtC1);
    k_prep_wcat<<<(128 * 1152 + 255) / 256, 256, 0, stream>>>(W02, W2, WtC2);
    k_prep_wt<<<(128 * 128 + 255) / 256, 256, 0, stream>>>(p1w, Wtp1, 128);
    k_prep_wt<<<(128 * 128 + 255) / 256, 256, 0, stream>>>(p2w, Wtp2, 128);
    k_prep_wt<<<(64 * 128 + 255) / 256, 256, 0, stream>>>(ow, WtO, 64);

    const int GAGG = (NN + 3) / 4;   // 12500 blocks, wave per node

    // ---- layer 1 ----
    k_aggw<<<GAGG, 256, 0, stream>>>(T1, AW, off8, esrcF);
    k_mfma<128, 0, 9><<<GRIDM, 256, 0, stream>>>(
        (const short*)T1, (const short*)AW, (const short*)WtC1,
        Hf, (unsigned short*)T2, nullptr, nullptr, nullptr, invdeg);
    k_aggh<<<GAGG, 256, 0, stream>>>(T2, AH, off8, esrcF, invdeg);
    k_mfma<128, 1, 1><<<GRIDM, 256, 0, stream>>>(
        (const short*)AH, nullptr, (const short*)Wtp1,
        nullptr, (unsigned short*)T3, Hf, p1b, al1, nullptr);

    // ---- layer 2 ----
    k_aggw<<<GAGG, 256, 0, stream>>>(T3, AW, off8, esrcF);
    k_mfma<128, 0, 9><<<GRIDM, 256, 0, stream>>>(
        (const short*)T3, (const short*)AW, (const short*)WtC2,
        Hf, (unsigned short*)T1, nullptr, nullptr, nullptr, invdeg);
    k_aggh<<<GAGG, 256, 0, stream>>>(T1, AH, off8, esrcF, invdeg);
    k_mfma<128, 1, 1><<<GRIDM, 256, 0, stream>>>(
        (const short*)AH, nullptr, (const short*)Wtp2,
        nullptr, (unsigned short*)T2, Hf, p2b, al2, nullptr);

    // ---- final projection ----
    k_mfma<64, 2, 1><<<GRIDM, 256, 0, stream>>>(
        (const short*)T2, nullptr, (const short*)WtO,
        out, nullptr, nullptr, ob, nullptr, nullptr);
}